// Round 3
// baseline (318.960 us; speedup 1.0000x reference)
//
#include <hip/hip_runtime.h>

// net_86698209837440: N=100000, DEG=32 (edges sorted by tgt, deg==32), D=24, NK=2, H=64.
// R3: one THREAD per (node, edge-half). No shuffles. float4 gathers, float4 accums.
// Reduction + pre staging through LDS, then per-lane-h matmul vs register-resident W.

#define NN   100000
#define DEG  32
#define EE   (NN * DEG)
#define DD   24
#define HH   64
#define NPB  128      // nodes per block (256 thr = 128 nodes x 2 edge-halves)
#define TPB  256
#define LSTR 76       // LDS row stride in floats (16B-aligned, bank-spread)

__device__ __forceinline__ void fma4(float4& a, float c, const float4 v) {
    a.x += c * v.x; a.y += c * v.y; a.z += c * v.z; a.w += c * v.w;
}
__device__ __forceinline__ void add4(float4& a, const float4 v) {
    a.x += v.x; a.y += v.y; a.z += v.z; a.w += v.w;
}

__global__ __launch_bounds__(TPB, 3) void gnn_fused(
    const float* __restrict__ x,          // [N, 24]
    const int*   __restrict__ edge_index, // [2, E]; row 0 = src
    const float* __restrict__ kv,         // [2, E]
    const float* __restrict__ W,          // [64, 48]
    float*       __restrict__ out)        // [N, 64]
{
    __shared__ float buf[NPB * LSTR];     // 38912 B

    const int t    = threadIdx.x;
    const int nl   = t & (NPB - 1);       // node-local 0..127
    const int h    = t >> 7;              // edge-half 0/1 (wave-uniform)
    const int nodeBase = blockIdx.x * NPB;
    const int node  = nodeBase + nl;
    const int nodeC = (node < NN) ? node : (NN - 1);   // clamped for addressing

    const float* k1p = kv + EE;

    float4 a0[6], a1[6], sm[6];
    #pragma unroll
    for (int q = 0; q < 6; ++q) {
        a0[q] = make_float4(0.f, 0.f, 0.f, 0.f);
        a1[q] = make_float4(0.f, 0.f, 0.f, 0.f);
        sm[q] = make_float4(0.f, 0.f, 0.f, 0.f);
    }

    // ---- Phase 1: this thread accumulates 16 edges of its node (2 chunks of 8)
    const int ebase = nodeC * DEG + h * 16;
    #pragma unroll
    for (int sc = 0; sc < 2; ++sc) {
        const int eo = ebase + sc * 8;    // 32B-aligned offsets
        const int4   sA  = ((const int4*)(edge_index + eo))[0];
        const int4   sB  = ((const int4*)(edge_index + eo))[1];
        const float4 c0A = ((const float4*)(kv  + eo))[0];
        const float4 c0B = ((const float4*)(kv  + eo))[1];
        const float4 c1A = ((const float4*)(k1p + eo))[0];
        const float4 c1B = ((const float4*)(k1p + eo))[1];
        const int   sv[8] = { sA.x, sA.y, sA.z, sA.w, sB.x, sB.y, sB.z, sB.w };
        const float c0v[8] = { c0A.x, c0A.y, c0A.z, c0A.w, c0B.x, c0B.y, c0B.z, c0B.w };
        const float c1v[8] = { c1A.x, c1A.y, c1A.z, c1A.w, c1B.x, c1B.y, c1B.z, c1B.w };

        #pragma unroll
        for (int j = 0; j < 8; ++j) {
            const float4* xr = (const float4*)(x + sv[j] * DD);  // 96B row, 16B-aligned
            float4 v0 = xr[0], v1 = xr[1], v2 = xr[2], v3 = xr[3], v4 = xr[4], v5 = xr[5];
            const float c0 = c0v[j], c1 = c1v[j];
            fma4(a0[0], c0, v0); fma4(a1[0], c1, v0); add4(sm[0], v0);
            fma4(a0[1], c0, v1); fma4(a1[1], c1, v1); add4(sm[1], v1);
            fma4(a0[2], c0, v2); fma4(a1[2], c1, v2); add4(sm[2], v2);
            fma4(a0[3], c0, v3); fma4(a1[3], c1, v3); add4(sm[3], v3);
            fma4(a0[4], c0, v4); fma4(a1[4], c1, v4); add4(sm[4], v4);
            fma4(a0[5], c0, v5); fma4(a1[5], c1, v5); add4(sm[5], v5);
        }
    }

    // ---- Reduction: h=1 publishes partials; h=0 combines, normalizes, writes pre[48]
    float4* row = (float4*)(buf + nl * LSTR);   // 304B row stride, 16B-aligned
    if (h == 1) {                               // wave-uniform branch (waves 2,3)
        #pragma unroll
        for (int q = 0; q < 6; ++q) {
            row[q]      = a0[q];
            row[6 + q]  = a1[q];
            row[12 + q] = sm[q];
        }
    }
    __syncthreads();
    if (h == 0) {
        const float4* xr = (const float4*)(x + nodeC * DD);
        #pragma unroll
        for (int q = 0; q < 6; ++q) {
            add4(a0[q], row[q]);
            add4(a1[q], row[6 + q]);
            add4(sm[q], row[12 + q]);
            const float4 xs = xr[q];
            float4 p0, p1;
            p0.x = a0[q].x - sm[q].x * (1.f/32.f) + xs.x;
            p0.y = a0[q].y - sm[q].y * (1.f/32.f) + xs.y;
            p0.z = a0[q].z - sm[q].z * (1.f/32.f) + xs.z;
            p0.w = a0[q].w - sm[q].w * (1.f/32.f) + xs.w;
            p1.x = a1[q].x - sm[q].x * (1.f/32.f) + xs.x;
            p1.y = a1[q].y - sm[q].y * (1.f/32.f) + xs.y;
            p1.z = a1[q].z - sm[q].z * (1.f/32.f) + xs.z;
            p1.w = a1[q].w - sm[q].w * (1.f/32.f) + xs.w;
            row[q]     = p0;      // pre[0..24): same thread read-then-write, no hazard
            row[6 + q] = p1;      // pre[24..48)
        }
    }
    __syncthreads();

    // ---- Phase 2: out[node][lane] = pre[node][:] . W[lane][:]
    const int lane = t & 63;
    const int wid  = t >> 6;
    float Wreg[48];
    {
        const float4* wp = (const float4*)W;     // row = 192B
        #pragma unroll
        for (int q = 0; q < 12; ++q) {
            const float4 ww = wp[lane * 12 + q];
            Wreg[q*4+0] = ww.x; Wreg[q*4+1] = ww.y; Wreg[q*4+2] = ww.z; Wreg[q*4+3] = ww.w;
        }
    }
    for (int i = 0; i < NPB / 4; ++i) {
        const int n  = wid + 4 * i;
        const int gn = nodeBase + n;
        const float4* pr = (const float4*)(buf + n * LSTR);   // broadcast reads
        float acc = 0.f;
        #pragma unroll
        for (int q = 0; q < 12; ++q) {
            const float4 pv = pr[q];
            acc += pv.x * Wreg[q*4+0] + pv.y * Wreg[q*4+1]
                 + pv.z * Wreg[q*4+2] + pv.w * Wreg[q*4+3];
        }
        if (gn < NN) out[(size_t)gn * HH + lane] = acc;
    }
}

extern "C" void kernel_launch(void* const* d_in, const int* in_sizes, int n_in,
                              void* d_out, int out_size, void* d_ws, size_t ws_size,
                              hipStream_t stream) {
    const float* x  = (const float*)d_in[0];
    const int*   ei = (const int*)d_in[1];
    const float* kv = (const float*)d_in[2];
    const float* W  = (const float*)d_in[3];
    float* out = (float*)d_out;

    const int grid = (NN + NPB - 1) / NPB;   // 782
    gnn_fused<<<grid, TPB, 0, stream>>>(x, ei, kv, W, out);
}

// Round 4
// 154.369 us; speedup vs baseline: 2.0662x; 2.0662x over previous
//
#include <hip/hip_runtime.h>

// net_86698209837440: N=100000, DEG=32 (edges sorted by tgt, deg==32), D=24, NK=2, H=64.
// R4: MFMA everywhere. Phase 1: per node, [k0;k1;ones](3x32) @ gathered-x(32x24) via
// 2x mfma_f32_32x32x16_bf16. x pre-converted to bf16 in d_ws (4.8MB ~ fits XCD L2),
// gathers are 2B/lane wave-coalesced. Phase 2: pre[64x48]bf16 (LDS) @ W^T via MFMA.
// fp32 accumulation throughout; bf16 rounding attenuated by W (~+0.03 absmax).

#define NN   100000
#define DEG  32
#define EE   (NN * DEG)
#define DD   24
#define HH   64
#define NPB  64            // nodes per block
#define TPB  256
#define NPW  16            // nodes per wave (4 waves)

typedef __attribute__((ext_vector_type(8)))  short short8;
typedef __attribute__((ext_vector_type(16))) float float16;

__device__ __forceinline__ unsigned short f2bf(float f) {
    union { float f; unsigned u; } v; v.f = f;
    unsigned r = v.u + 0x7fffu + ((v.u >> 16) & 1u);   // RNE
    return (unsigned short)(r >> 16);
}

// ---- pre-pass: x fp32 -> bf16 (RNE) into workspace. N*D = 2.4M, /4 = 600000.
__global__ void xcvt(const float* __restrict__ x, unsigned short* __restrict__ xb, int n4) {
    int i = blockIdx.x * blockDim.x + threadIdx.x;
    if (i < n4) {
        float4 v = ((const float4*)x)[i];
        ushort4 o;
        o.x = f2bf(v.x); o.y = f2bf(v.y); o.z = f2bf(v.z); o.w = f2bf(v.w);
        ((ushort4*)xb)[i] = o;
    }
}

template<bool XBF>
__global__ __launch_bounds__(TPB, 4) void gnn(
    const float*          __restrict__ x,    // [N,24] fp32 (epilogue + fallback)
    const unsigned short* __restrict__ xb,   // [N,24] bf16 (gather path, if XBF)
    const int*            __restrict__ ei,   // [2,E]; row 0 = src
    const float*          __restrict__ kv,   // [2,E]
    const float*          __restrict__ W,    // [64,48]
    float*                __restrict__ out)  // [N,64]
{
    __shared__ unsigned short pre_s[NPB * 48];   // 6 KB, bf16 pre rows (96B stride)

    const int t    = threadIdx.x;
    const int lane = t & 63;
    const int w    = t >> 6;
    const int m    = lane & 31;      // A-row / B-col / C-col index
    const int kh   = lane >> 5;      // K-half
    const int base = blockIdx.x * NPB;
    const float* kv1 = kv + EE;
    const int dclamp = (m < DD) ? m : (DD - 1);  // cols 24-31 are junk, never used

    // ================= Phase 1: aggregation via MFMA, one node at a time =================
    for (int i = 0; i < NPW; ++i) {
        const int nl = w * NPW + i;
        int node = base + nl; if (node >= NN) node = NN - 1;   // tail dup, stores guarded
        const int eb = node * DEG;

        float16 acc;
        #pragma unroll
        for (int r = 0; r < 16; ++r) acc[r] = 0.f;

        #pragma unroll
        for (int kc = 0; kc < 2; ++kc) {
            const int e0 = eb + kc * 16 + kh * 8;

            // ---- A fragment: row m of [k0; k1; ones; 0...], k = kh*8+j
            short8 afrag;
            if (m < 2) {
                const float* ar = (m == 0 ? kv : kv1) + e0;
                const float4 cA = ((const float4*)ar)[0];
                const float4 cB = ((const float4*)ar)[1];
                afrag[0] = (short)f2bf(cA.x); afrag[1] = (short)f2bf(cA.y);
                afrag[2] = (short)f2bf(cA.z); afrag[3] = (short)f2bf(cA.w);
                afrag[4] = (short)f2bf(cB.x); afrag[5] = (short)f2bf(cB.y);
                afrag[6] = (short)f2bf(cB.z); afrag[7] = (short)f2bf(cB.w);
            } else if (m == 2) {
                #pragma unroll
                for (int j = 0; j < 8; ++j) afrag[j] = (short)0x3F80;  // bf16 1.0
            } else {
                #pragma unroll
                for (int j = 0; j < 8; ++j) afrag[j] = 0;
            }

            // ---- B fragment: B[k][n] = x[src[e0+j]][n], n = m (clamped)
            const int4 sA = ((const int4*)(ei + e0))[0];   // uniform per half-wave
            const int4 sB = ((const int4*)(ei + e0))[1];
            const int sv[8] = { sA.x, sA.y, sA.z, sA.w, sB.x, sB.y, sB.z, sB.w };
            short8 bfrag;
            #pragma unroll
            for (int j = 0; j < 8; ++j) {
                if (XBF) bfrag[j] = (short)xb[sv[j] * DD + dclamp];     // coalesced 2B
                else     bfrag[j] = (short)f2bf(x[sv[j] * DD + dclamp]);
            }

            acc = __builtin_amdgcn_mfma_f32_32x32x16_bf16(afrag, bfrag, acc, 0, 0, 0);
        }

        // ---- epilogue: lanes kh==0 hold rows 0(a0),1(a1),2(sum) for dim=m
        if (kh == 0 && m < DD) {
            const float sm = acc[2] * (1.f / 32.f);
            const float xv = x[node * DD + m];
            pre_s[nl * 48 + m]      = f2bf(acc[0] - sm + xv);
            pre_s[nl * 48 + 24 + m] = f2bf(acc[1] - sm + xv);
        }
    }
    __syncthreads();

    // ================= Phase 2: out[64 nodes][64 h] = pre @ W^T via MFMA =================
    {
        const int mt = w >> 1;            // node tile (32 nodes)
        const int nt = w & 1;             // h tile (32 outputs)
        const int h  = nt * 32 + m;

        float16 acc;
        #pragma unroll
        for (int r = 0; r < 16; ++r) acc[r] = 0.f;

        #pragma unroll
        for (int kc = 0; kc < 3; ++kc) {
            const int c0 = kc * 16 + kh * 8;
            // A: pre rows from LDS (16B-aligned: 96B row stride, c0*2B in {0,16,..,80})
            const short8 af = *((const short8*)(pre_s + (mt * 32 + m) * 48 + c0));
            // B: W[h][c0..c0+7] fp32 -> bf16
            const float* wr = W + h * 48 + c0;
            const float4 wA = ((const float4*)wr)[0];
            const float4 wB = ((const float4*)wr)[1];
            short8 bf;
            bf[0] = (short)f2bf(wA.x); bf[1] = (short)f2bf(wA.y);
            bf[2] = (short)f2bf(wA.z); bf[3] = (short)f2bf(wA.w);
            bf[4] = (short)f2bf(wB.x); bf[5] = (short)f2bf(wB.y);
            bf[6] = (short)f2bf(wB.z); bf[7] = (short)f2bf(wB.w);
            acc = __builtin_amdgcn_mfma_f32_32x32x16_bf16(af, bf, acc, 0, 0, 0);
        }

        #pragma unroll
        for (int r = 0; r < 16; ++r) {
            const int row = (r & 3) + 8 * (r >> 2) + 4 * kh;   // node within tile
            const int gn  = base + mt * 32 + row;
            if (gn < NN) out[gn * HH + h] = acc[r];
        }
    }
}

extern "C" void kernel_launch(void* const* d_in, const int* in_sizes, int n_in,
                              void* d_out, int out_size, void* d_ws, size_t ws_size,
                              hipStream_t stream) {
    const float* x  = (const float*)d_in[0];
    const int*   ei = (const int*)d_in[1];
    const float* kv = (const float*)d_in[2];
    const float* W  = (const float*)d_in[3];
    float* out = (float*)d_out;

    const size_t xb_bytes = (size_t)NN * DD * sizeof(unsigned short);  // 4.8 MB
    const int grid = (NN + NPB - 1) / NPB;                             // 1563

    if (ws_size >= xb_bytes) {
        unsigned short* xb = (unsigned short*)d_ws;
        const int n4 = NN * DD / 4;                                    // 600000
        xcvt<<<(n4 + 255) / 256, 256, 0, stream>>>(x, xb, n4);
        gnn<true><<<grid, TPB, 0, stream>>>(x, xb, ei, kv, W, out);
    } else {
        gnn<false><<<grid, TPB, 0, stream>>>(x, nullptr, ei, kv, W, out);
    }
}

// Round 5
// 153.111 us; speedup vs baseline: 2.0832x; 1.0082x over previous
//
#include <hip/hip_runtime.h>

// net_86698209837440: N=100000, DEG=32 (edges sorted by tgt, deg==32), D=24, NK=2, H=64.
// R5: same MFMA structure as R4, but gather serialization fixed:
//  - B-fragment gathers load into 8 INDEPENDENT 32-bit VGPRs (zero-extended ushort),
//    packed to bf16x8 afterwards -> all 16 gathers/node in flight at once
//    (R4's d16 short8 packing left VGPR_Count=32 => waitcnt-serialized round trips).
//  - #pragma unroll 2 on the node loop for cross-node latency overlap.
// Phase 1: [k0;k1;ones](3x32) @ gathered-x(32x24) via 2x mfma_f32_32x32x16_bf16.
// Phase 2: pre[64x48]bf16 (LDS) @ W^T via MFMA. fp32 accumulation throughout.

#define NN   100000
#define DEG  32
#define EE   (NN * DEG)
#define DD   24
#define HH   64
#define NPB  64            // nodes per block
#define TPB  256
#define NPW  16            // nodes per wave (4 waves)

typedef __attribute__((ext_vector_type(8)))  short short8;
typedef __attribute__((ext_vector_type(16))) float float16;

__device__ __forceinline__ unsigned short f2bf(float f) {
    union { float f; unsigned u; } v; v.f = f;
    unsigned r = v.u + 0x7fffu + ((v.u >> 16) & 1u);   // RNE
    return (unsigned short)(r >> 16);
}

__device__ __forceinline__ short8 pack8(unsigned g0, unsigned g1, unsigned g2, unsigned g3,
                                        unsigned g4, unsigned g5, unsigned g6, unsigned g7) {
    union { unsigned u[4]; short8 s; } p;
    p.u[0] = g0 | (g1 << 16);
    p.u[1] = g2 | (g3 << 16);
    p.u[2] = g4 | (g5 << 16);
    p.u[3] = g6 | (g7 << 16);
    return p.s;
}

// ---- pre-pass: x fp32 -> bf16 (RNE) into workspace. N*D = 2.4M, /4 = 600000.
__global__ void xcvt(const float* __restrict__ x, unsigned short* __restrict__ xb, int n4) {
    int i = blockIdx.x * blockDim.x + threadIdx.x;
    if (i < n4) {
        float4 v = ((const float4*)x)[i];
        ushort4 o;
        o.x = f2bf(v.x); o.y = f2bf(v.y); o.z = f2bf(v.z); o.w = f2bf(v.w);
        ((ushort4*)xb)[i] = o;
    }
}

__global__ __launch_bounds__(TPB, 4) void gnn(
    const float*          __restrict__ x,    // [N,24] fp32 (epilogue)
    const unsigned short* __restrict__ xb,   // [N,24] bf16 (gather path)
    const int*            __restrict__ ei,   // [2,E]; row 0 = src
    const float*          __restrict__ kv,   // [2,E]
    const float*          __restrict__ W,    // [64,48]
    float*                __restrict__ out)  // [N,64]
{
    __shared__ unsigned short pre_s[NPB * 48];   // 6 KB, bf16 pre rows (96B stride)

    const int t    = threadIdx.x;
    const int lane = t & 63;
    const int w    = t >> 6;
    const int m    = lane & 31;      // A-row / B-col / C-col index
    const int kh   = lane >> 5;      // K-half
    const int base = blockIdx.x * NPB;
    const float* kv1 = kv + EE;
    const int dclamp = (m < DD) ? m : (DD - 1);  // cols 24-31 are junk, never used

    // ================= Phase 1: aggregation via MFMA =================
    #pragma unroll 2
    for (int i = 0; i < NPW; ++i) {
        const int nl = w * NPW + i;
        int node = base + nl; if (node >= NN) node = NN - 1;   // tail dup, stores guarded
        const int eb = node * DEG;

        float16 acc;
        #pragma unroll
        for (int r = 0; r < 16; ++r) acc[r] = 0.f;

        #pragma unroll
        for (int kc = 0; kc < 2; ++kc) {
            const int e0 = eb + kc * 16 + kh * 8;

            // ---- A fragment: row m of [k0; k1; ones; 0...], k = kh*8+j
            short8 afrag;
            if (m < 2) {
                const float* ar = (m == 0 ? kv : kv1) + e0;
                const float4 cA = ((const float4*)ar)[0];
                const float4 cB = ((const float4*)ar)[1];
                afrag = pack8(f2bf(cA.x), f2bf(cA.y), f2bf(cA.z), f2bf(cA.w),
                              f2bf(cB.x), f2bf(cB.y), f2bf(cB.z), f2bf(cB.w));
            } else if (m == 2) {
                unsigned one2 = 0x3F803F80u;  // bf16 1.0 x2
                union { unsigned u[4]; short8 s; } p;
                p.u[0] = one2; p.u[1] = one2; p.u[2] = one2; p.u[3] = one2;
                afrag = p.s;
            } else {
                union { unsigned u[4]; short8 s; } p;
                p.u[0] = 0; p.u[1] = 0; p.u[2] = 0; p.u[3] = 0;
                afrag = p.s;
            }

            // ---- B fragment: B[k][n] = xb[src[e0+j]][n], n = m (clamped).
            // 8 independent zero-extended loads into full VGPRs, pack afterwards.
            const int4 sA = ((const int4*)(ei + e0))[0];
            const int4 sB = ((const int4*)(ei + e0))[1];
            const unsigned g0 = xb[sA.x * DD + dclamp];
            const unsigned g1 = xb[sA.y * DD + dclamp];
            const unsigned g2 = xb[sA.z * DD + dclamp];
            const unsigned g3 = xb[sA.w * DD + dclamp];
            const unsigned g4 = xb[sB.x * DD + dclamp];
            const unsigned g5 = xb[sB.y * DD + dclamp];
            const unsigned g6 = xb[sB.z * DD + dclamp];
            const unsigned g7 = xb[sB.w * DD + dclamp];
            const short8 bfrag = pack8(g0, g1, g2, g3, g4, g5, g6, g7);

            acc = __builtin_amdgcn_mfma_f32_32x32x16_bf16(afrag, bfrag, acc, 0, 0, 0);
        }

        // ---- epilogue: lanes kh==0 hold rows 0(a0),1(a1),2(sum) for dim=m
        if (kh == 0 && m < DD) {
            const float sm = acc[2] * (1.f / 32.f);
            const float xv = x[node * DD + m];
            pre_s[nl * 48 + m]      = f2bf(acc[0] - sm + xv);
            pre_s[nl * 48 + 24 + m] = f2bf(acc[1] - sm + xv);
        }
    }
    __syncthreads();

    // ================= Phase 2: out[64 nodes][64 h] = pre @ W^T via MFMA =================
    {
        const int mt = w >> 1;            // node tile (32 nodes)
        const int nt = w & 1;             // h tile (32 outputs)
        const int h  = nt * 32 + m;

        float16 acc;
        #pragma unroll
        for (int r = 0; r < 16; ++r) acc[r] = 0.f;

        #pragma unroll
        for (int kc = 0; kc < 3; ++kc) {
            const int c0 = kc * 16 + kh * 8;
            // A: pre rows from LDS (96B row stride, offsets 16B-aligned)
            const short8 af = *((const short8*)(pre_s + (mt * 32 + m) * 48 + c0));
            // B: W[h][c0..c0+7] fp32 -> bf16
            const float* wr = W + h * 48 + c0;
            const float4 wA = ((const float4*)wr)[0];
            const float4 wB = ((const float4*)wr)[1];
            const short8 bf = pack8(f2bf(wA.x), f2bf(wA.y), f2bf(wA.z), f2bf(wA.w),
                                    f2bf(wB.x), f2bf(wB.y), f2bf(wB.z), f2bf(wB.w));
            acc = __builtin_amdgcn_mfma_f32_32x32x16_bf16(af, bf, acc, 0, 0, 0);
        }

        #pragma unroll
        for (int r = 0; r < 16; ++r) {
            const int row = (r & 3) + 8 * (r >> 2) + 4 * kh;   // node within tile
            const int gn  = base + mt * 32 + row;
            if (gn < NN) out[gn * HH + h] = acc[r];
        }
    }
}

extern "C" void kernel_launch(void* const* d_in, const int* in_sizes, int n_in,
                              void* d_out, int out_size, void* d_ws, size_t ws_size,
                              hipStream_t stream) {
    const float* x  = (const float*)d_in[0];
    const int*   ei = (const int*)d_in[1];
    const float* kv = (const float*)d_in[2];
    const float* W  = (const float*)d_in[3];
    float* out = (float*)d_out;

    unsigned short* xb = (unsigned short*)d_ws;            // 4.8 MB, ws is plentiful
    const int n4 = NN * DD / 4;                            // 600000
    xcvt<<<(n4 + 255) / 256, 256, 0, stream>>>(x, xb, n4);

    const int grid = (NN + NPB - 1) / NPB;                 // 1563
    gnn<<<grid, TPB, 0, stream>>>(x, xb, ei, kv, W, out);
}

// Round 6
// 127.899 us; speedup vs baseline: 2.4938x; 1.1971x over previous
//
#include <hip/hip_runtime.h>

// net_86698209837440: N=100000, DEG=32 (edges sorted by tgt, deg==32), D=24, NK=2, H=64.
// R6: break the per-node latency chain structurally.
//  - ei + kvals(bf16) staged to LDS at block start (coalesced) -> no global dep chain.
//  - depth-2 explicit pipeline: node i+1 gathers live across node i MFMAs (SSA, full unroll).
//  - NPB=32, grid=3125 (exact): 12500 waves, removes grid-limited occupancy (was 53%).
// Phase 1: [k0;k1;ones](3x32) @ gathered-x(32x24) via 2x mfma_f32_32x32x16_bf16 per node.
// Phase 2: pre(32x48 bf16, LDS) @ W^T via 3x MFMA on waves 0,1. fp32 accumulation.

#define NN   100000
#define DEG  32
#define EE   (NN * DEG)
#define DD   24
#define HH   64
#define NPB  32            // nodes per block; 100000 = 3125 * 32 exact
#define TPB  256
#define NPW  8             // nodes per wave

typedef __attribute__((ext_vector_type(8)))  short short8;
typedef __attribute__((ext_vector_type(16))) float float16;

__device__ __forceinline__ unsigned short f2bf(float f) {
    union { float f; unsigned u; } v; v.f = f;
    unsigned r = v.u + 0x7fffu + ((v.u >> 16) & 1u);   // RNE
    return (unsigned short)(r >> 16);
}

__device__ __forceinline__ short8 pack8(unsigned g0, unsigned g1, unsigned g2, unsigned g3,
                                        unsigned g4, unsigned g5, unsigned g6, unsigned g7) {
    union { unsigned u[4]; short8 s; } p;
    p.u[0] = g0 | (g1 << 16);
    p.u[1] = g2 | (g3 << 16);
    p.u[2] = g4 | (g5 << 16);
    p.u[3] = g6 | (g7 << 16);
    return p.s;
}

__device__ __forceinline__ short8 const8(unsigned v) {
    union { unsigned u[4]; short8 s; } p;
    p.u[0] = v; p.u[1] = v; p.u[2] = v; p.u[3] = v;
    return p.s;
}

// ---- pre-pass: x fp32 -> bf16 (RNE) into workspace.
__global__ void xcvt(const float* __restrict__ x, unsigned short* __restrict__ xb, int n4) {
    int i = blockIdx.x * blockDim.x + threadIdx.x;
    if (i < n4) {
        float4 v = ((const float4*)x)[i];
        ushort4 o;
        o.x = f2bf(v.x); o.y = f2bf(v.y); o.z = f2bf(v.z); o.w = f2bf(v.w);
        ((ushort4*)xb)[i] = o;
    }
}

__global__ __launch_bounds__(TPB, 4) void gnn(
    const float*          __restrict__ x,    // [N,24] fp32 (epilogue)
    const unsigned short* __restrict__ xb,   // [N,24] bf16 (gather table)
    const int*            __restrict__ ei,   // [2,E]; row 0 = src
    const float*          __restrict__ kv,   // [2,E]
    const float*          __restrict__ W,    // [64,48]
    float*                __restrict__ out)  // [N,64]
{
    __shared__ int            ei_s[NPB * DEG];       // 4 KB src indices for this block
    __shared__ unsigned short kv_s[2 * NPB * DEG];   // 4 KB bf16 kvals
    __shared__ unsigned short pre_s[NPB * 48];       // 3 KB bf16 pre rows

    const int t    = threadIdx.x;
    const int lane = t & 63;
    const int w    = t >> 6;
    const int m    = lane & 31;      // A-row / B-col / C-col
    const int kh   = lane >> 5;      // K-half
    const int kh8  = kh * 8;
    const int base = blockIdx.x * NPB;
    const int dclamp = (m < DD) ? m : (DD - 1);

    // ---- cooperative staging: ei row0 + both kv rows (converted to bf16)
    {
        const size_t eb = (size_t)base * DEG;        // 1024 edges per block
        const int4 ev = ((const int4*)(ei + eb))[t];
        ((int4*)ei_s)[t] = ev;
        const float4 c0 = ((const float4*)(kv + eb))[t];
        const float4 c1 = ((const float4*)(kv + EE + eb))[t];
        ushort4 u0, u1;
        u0.x = f2bf(c0.x); u0.y = f2bf(c0.y); u0.z = f2bf(c0.z); u0.w = f2bf(c0.w);
        u1.x = f2bf(c1.x); u1.y = f2bf(c1.y); u1.z = f2bf(c1.z); u1.w = f2bf(c1.w);
        ((ushort4*)kv_s)[t] = u0;
        ((ushort4*)(kv_s + NPB * DEG))[t] = u1;
    }
    __syncthreads();

    // ================= Phase 1: depth-2 pipelined aggregation =================
    const unsigned short* kvrow = kv_s + (m & 1) * (NPB * DEG);  // m=0 -> k0, m=1 -> k1

    unsigned g[2][16];
    float    xv[2];

    // load stage for node index nl into slot sl
    #define LOAD_NODE(nl, sl) do {                                             \
        const int el_ = (nl) * DEG + kh8;                                      \
        const int4 s0_ = *(const int4*)(ei_s + el_);                           \
        const int4 s1_ = *(const int4*)(ei_s + el_ + 4);                       \
        const int4 s2_ = *(const int4*)(ei_s + el_ + 16);                      \
        const int4 s3_ = *(const int4*)(ei_s + el_ + 20);                      \
        g[sl][0]  = xb[s0_.x * DD + dclamp];                                   \
        g[sl][1]  = xb[s0_.y * DD + dclamp];                                   \
        g[sl][2]  = xb[s0_.z * DD + dclamp];                                   \
        g[sl][3]  = xb[s0_.w * DD + dclamp];                                   \
        g[sl][4]  = xb[s1_.x * DD + dclamp];                                   \
        g[sl][5]  = xb[s1_.y * DD + dclamp];                                   \
        g[sl][6]  = xb[s1_.z * DD + dclamp];                                   \
        g[sl][7]  = xb[s1_.w * DD + dclamp];                                   \
        g[sl][8]  = xb[s2_.x * DD + dclamp];                                   \
        g[sl][9]  = xb[s2_.y * DD + dclamp];                                   \
        g[sl][10] = xb[s2_.z * DD + dclamp];                                   \
        g[sl][11] = xb[s2_.w * DD + dclamp];                                   \
        g[sl][12] = xb[s3_.x * DD + dclamp];                                   \
        g[sl][13] = xb[s3_.y * DD + dclamp];                                   \
        g[sl][14] = xb[s3_.z * DD + dclamp];                                   \
        g[sl][15] = xb[s3_.w * DD + dclamp];                                   \
        xv[sl] = x[(base + (nl)) * DD + dclamp];                               \
    } while (0)

    LOAD_NODE(w * NPW, 0);

    #pragma unroll
    for (int i = 0; i < NPW; ++i) {
        const int cur = i & 1;
        const int nl  = w * NPW + i;
        if (i < NPW - 1) LOAD_NODE(nl + 1, cur ^ 1);   // prefetch next node

        // A fragments from LDS (2-way broadcast, conflict-free)
        const int el = nl * DEG + kh8;
        short8 raw0 = *(const short8*)(kvrow + el);
        short8 raw1 = *(const short8*)(kvrow + el + 16);
        const short8 af0 = (m < 2) ? raw0 : const8(m == 2 ? 0x3F803F80u : 0u);
        const short8 af1 = (m < 2) ? raw1 : const8(m == 2 ? 0x3F803F80u : 0u);

        const short8 bf0 = pack8(g[cur][0], g[cur][1], g[cur][2],  g[cur][3],
                                 g[cur][4], g[cur][5], g[cur][6],  g[cur][7]);
        const short8 bf1 = pack8(g[cur][8], g[cur][9], g[cur][10], g[cur][11],
                                 g[cur][12], g[cur][13], g[cur][14], g[cur][15]);

        float16 acc;
        #pragma unroll
        for (int r = 0; r < 16; ++r) acc[r] = 0.f;
        acc = __builtin_amdgcn_mfma_f32_32x32x16_bf16(af0, bf0, acc, 0, 0, 0);
        acc = __builtin_amdgcn_mfma_f32_32x32x16_bf16(af1, bf1, acc, 0, 0, 0);

        // rows 0(a0),1(a1),2(sum) live in regs 0,1,2 of kh==0 lanes
        if (kh == 0 && m < DD) {
            const float sm = acc[2] * (1.f / 32.f);
            const float pv = xv[cur] - sm;
            pre_s[nl * 48 + m]      = f2bf(acc[0] + pv);
            pre_s[nl * 48 + 24 + m] = f2bf(acc[1] + pv);
        }
    }
    #undef LOAD_NODE
    __syncthreads();

    // ================= Phase 2: out(32x64) = pre(32x48) @ W^T, waves 0,1 =================
    if (w < 2) {
        const int h = w * 32 + m;

        float16 acc;
        #pragma unroll
        for (int r = 0; r < 16; ++r) acc[r] = 0.f;

        #pragma unroll
        for (int kc = 0; kc < 3; ++kc) {
            const int c0 = kc * 16 + kh8;
            const short8 af = *(const short8*)(pre_s + m * 48 + c0);
            const float* wr = W + h * 48 + c0;
            const float4 wA = ((const float4*)wr)[0];
            const float4 wB = ((const float4*)wr)[1];
            const short8 bf = pack8(f2bf(wA.x), f2bf(wA.y), f2bf(wA.z), f2bf(wA.w),
                                    f2bf(wB.x), f2bf(wB.y), f2bf(wB.z), f2bf(wB.w));
            acc = __builtin_amdgcn_mfma_f32_32x32x16_bf16(af, bf, acc, 0, 0, 0);
        }

        #pragma unroll
        for (int r = 0; r < 16; ++r) {
            const int row = (r & 3) + 8 * (r >> 2) + 4 * kh;   // node within block
            out[(size_t)(base + row) * HH + h] = acc[r];
        }
    }
}

extern "C" void kernel_launch(void* const* d_in, const int* in_sizes, int n_in,
                              void* d_out, int out_size, void* d_ws, size_t ws_size,
                              hipStream_t stream) {
    const float* x  = (const float*)d_in[0];
    const int*   ei = (const int*)d_in[1];
    const float* kv = (const float*)d_in[2];
    const float* W  = (const float*)d_in[3];
    float* out = (float*)d_out;

    unsigned short* xb = (unsigned short*)d_ws;            // 4.8 MB scratch
    const int n4 = NN * DD / 4;                            // 600000
    xcvt<<<(n4 + 255) / 256, 256, 0, stream>>>(x, xb, n4);

    const int grid = NN / NPB;                             // 3125, exact
    gnn<<<grid, TPB, 0, stream>>>(x, xb, ei, kv, W, out);
}

// Round 7
// 127.183 us; speedup vs baseline: 2.5079x; 1.0056x over previous
//
#include <hip/hip_runtime.h>

// net_86698209837440: N=100000, DEG=32 (edges sorted by tgt, deg==32), D=24, NK=2, H=64.
// R7 = R6 structure (LDS-staged ei/kv, depth-2 node pipeline, grid 3125) with
// per-gather VALU cut ~2x:
//  - ei_s holds PRE-SCALED byte offsets (src*48), computed once at staging
//    -> gather addr = 1 v_add (SGPR-base + 32-bit voffset), no v_mul per gather.
//  - bf16 pack via v_perm_b32 (1 op/pair) instead of shl+or.
//  - epilogue x read from bf16 xb (saves 4.8MB fetch).
//  - pre_s row stride 48->56 ushorts (112B): 8-way -> 4-way phase-2 conflicts.

#define NN   100000
#define DEG  32
#define EE   (NN * DEG)
#define DD   24
#define HH   64
#define NPB  32            // nodes per block; 100000 = 3125 * 32 exact
#define TPB  256
#define NPW  8             // nodes per wave
#define PST  56            // pre_s row stride (ushorts)

typedef __attribute__((ext_vector_type(8)))  short short8;
typedef __attribute__((ext_vector_type(16))) float float16;

__device__ __forceinline__ unsigned short f2bf(float f) {
    union { float f; unsigned u; } v; v.f = f;
    unsigned r = v.u + 0x7fffu + ((v.u >> 16) & 1u);   // RNE
    return (unsigned short)(r >> 16);
}

__device__ __forceinline__ float bf2f(unsigned u) {
    union { unsigned i; float f; } v; v.i = u << 16; return v.f;
}

// lo16(a) -> low half, lo16(b) -> high half, one v_perm_b32
__device__ __forceinline__ unsigned pk(unsigned a, unsigned b) {
    return __builtin_amdgcn_perm(b, a, 0x05040100u);
}

__device__ __forceinline__ short8 mk8(unsigned u0, unsigned u1, unsigned u2, unsigned u3) {
    union { unsigned u[4]; short8 s; } p;
    p.u[0] = u0; p.u[1] = u1; p.u[2] = u2; p.u[3] = u3;
    return p.s;
}

// ---- pre-pass: x fp32 -> bf16 (RNE) into workspace.
__global__ void xcvt(const float* __restrict__ x, unsigned short* __restrict__ xb, int n4) {
    int i = blockIdx.x * blockDim.x + threadIdx.x;
    if (i < n4) {
        float4 v = ((const float4*)x)[i];
        ushort4 o;
        o.x = f2bf(v.x); o.y = f2bf(v.y); o.z = f2bf(v.z); o.w = f2bf(v.w);
        ((ushort4*)xb)[i] = o;
    }
}

__global__ __launch_bounds__(TPB, 4) void gnn(
    const unsigned short* __restrict__ xb,   // [N,24] bf16 (gather table + epilogue)
    const int*            __restrict__ ei,   // [2,E]; row 0 = src
    const float*          __restrict__ kv,   // [2,E]
    const float*          __restrict__ W,    // [64,48]
    float*                __restrict__ out)  // [N,64]
{
    __shared__ int            ei_s[NPB * DEG];       // 4 KB: src*48 byte offsets
    __shared__ unsigned short kv_s[2 * NPB * DEG];   // 4 KB bf16 kvals
    __shared__ unsigned short pre_s[NPB * PST];      // 3.5 KB bf16 pre rows

    const int t    = threadIdx.x;
    const int lane = t & 63;
    const int w    = t >> 6;
    const int m    = lane & 31;      // A-row / B-col / C-col
    const int kh   = lane >> 5;      // K-half
    const int kh8  = kh * 8;
    const int base = blockIdx.x * NPB;
    const int dclamp = (m < DD) ? m : (DD - 1);
    const int m2     = dclamp * 2;   // byte offset within row
    const char* xbc  = (const char*)xb;

    // ---- cooperative staging: ei row0 (pre-scaled *48) + both kv rows (bf16)
    {
        const size_t eb = (size_t)base * DEG;        // 1024 edges per block
        int4 ev = ((const int4*)(ei + eb))[t];
        ev.x *= 48; ev.y *= 48; ev.z *= 48; ev.w *= 48;
        ((int4*)ei_s)[t] = ev;
        const float4 c0 = ((const float4*)(kv + eb))[t];
        const float4 c1 = ((const float4*)(kv + EE + eb))[t];
        ushort4 u0, u1;
        u0.x = f2bf(c0.x); u0.y = f2bf(c0.y); u0.z = f2bf(c0.z); u0.w = f2bf(c0.w);
        u1.x = f2bf(c1.x); u1.y = f2bf(c1.y); u1.z = f2bf(c1.z); u1.w = f2bf(c1.w);
        ((ushort4*)kv_s)[t] = u0;
        ((ushort4*)(kv_s + NPB * DEG))[t] = u1;
    }
    __syncthreads();

    // ================= Phase 1: depth-2 pipelined aggregation =================
    const unsigned short* kvrow = kv_s + (m & 1) * (NPB * DEG);  // m=0 -> k0, m=1 -> k1

    unsigned g[2][16];
    unsigned xv[2];

    #define LOAD_NODE(nl, sl) do {                                             \
        const int el_ = (nl) * DEG + kh8;                                      \
        const int4 s0_ = *(const int4*)(ei_s + el_);                           \
        const int4 s1_ = *(const int4*)(ei_s + el_ + 4);                       \
        const int4 s2_ = *(const int4*)(ei_s + el_ + 16);                      \
        const int4 s3_ = *(const int4*)(ei_s + el_ + 20);                      \
        g[sl][0]  = *(const unsigned short*)(xbc + (unsigned)(s0_.x + m2));    \
        g[sl][1]  = *(const unsigned short*)(xbc + (unsigned)(s0_.y + m2));    \
        g[sl][2]  = *(const unsigned short*)(xbc + (unsigned)(s0_.z + m2));    \
        g[sl][3]  = *(const unsigned short*)(xbc + (unsigned)(s0_.w + m2));    \
        g[sl][4]  = *(const unsigned short*)(xbc + (unsigned)(s1_.x + m2));    \
        g[sl][5]  = *(const unsigned short*)(xbc + (unsigned)(s1_.y + m2));    \
        g[sl][6]  = *(const unsigned short*)(xbc + (unsigned)(s1_.z + m2));    \
        g[sl][7]  = *(const unsigned short*)(xbc + (unsigned)(s1_.w + m2));    \
        g[sl][8]  = *(const unsigned short*)(xbc + (unsigned)(s2_.x + m2));    \
        g[sl][9]  = *(const unsigned short*)(xbc + (unsigned)(s2_.y + m2));    \
        g[sl][10] = *(const unsigned short*)(xbc + (unsigned)(s2_.z + m2));    \
        g[sl][11] = *(const unsigned short*)(xbc + (unsigned)(s2_.w + m2));    \
        g[sl][12] = *(const unsigned short*)(xbc + (unsigned)(s3_.x + m2));    \
        g[sl][13] = *(const unsigned short*)(xbc + (unsigned)(s3_.y + m2));    \
        g[sl][14] = *(const unsigned short*)(xbc + (unsigned)(s3_.z + m2));    \
        g[sl][15] = *(const unsigned short*)(xbc + (unsigned)(s3_.w + m2));    \
        xv[sl] = xb[(base + (nl)) * DD + dclamp];                              \
    } while (0)

    LOAD_NODE(w * NPW, 0);

    #pragma unroll
    for (int i = 0; i < NPW; ++i) {
        const int cur = i & 1;
        const int nl  = w * NPW + i;
        if (i < NPW - 1) LOAD_NODE(nl + 1, cur ^ 1);   // prefetch next node

        // A fragments from LDS (broadcast within half-wave, conflict-free)
        const int el = nl * DEG + kh8;
        const short8 raw0 = *(const short8*)(kvrow + el);
        const short8 raw1 = *(const short8*)(kvrow + el + 16);
        const unsigned fill = (m == 2) ? 0x3F803F80u : 0u;   // bf16 ones row / zeros
        const short8 af0 = (m < 2) ? raw0 : mk8(fill, fill, fill, fill);
        const short8 af1 = (m < 2) ? raw1 : mk8(fill, fill, fill, fill);

        const short8 bf0 = mk8(pk(g[cur][0],  g[cur][1]),  pk(g[cur][2],  g[cur][3]),
                               pk(g[cur][4],  g[cur][5]),  pk(g[cur][6],  g[cur][7]));
        const short8 bf1 = mk8(pk(g[cur][8],  g[cur][9]),  pk(g[cur][10], g[cur][11]),
                               pk(g[cur][12], g[cur][13]), pk(g[cur][14], g[cur][15]));

        float16 acc;
        #pragma unroll
        for (int r = 0; r < 16; ++r) acc[r] = 0.f;
        acc = __builtin_amdgcn_mfma_f32_32x32x16_bf16(af0, bf0, acc, 0, 0, 0);
        acc = __builtin_amdgcn_mfma_f32_32x32x16_bf16(af1, bf1, acc, 0, 0, 0);

        // rows 0(a0),1(a1),2(sum) live in regs 0,1,2 of kh==0 lanes
        if (kh == 0 && m < DD) {
            const float sm = acc[2] * (1.f / 32.f);
            const float pv = bf2f(xv[cur]) - sm;
            pre_s[nl * PST + m]      = f2bf(acc[0] + pv);
            pre_s[nl * PST + 24 + m] = f2bf(acc[1] + pv);
        }
    }
    #undef LOAD_NODE
    __syncthreads();

    // ================= Phase 2: out(32x64) = pre(32x48) @ W^T, waves 0,1 =================
    if (w < 2) {
        const int h = w * 32 + m;

        float16 acc;
        #pragma unroll
        for (int r = 0; r < 16; ++r) acc[r] = 0.f;

        #pragma unroll
        for (int kc = 0; kc < 3; ++kc) {
            const int c0 = kc * 16 + kh8;
            const short8 af = *(const short8*)(pre_s + m * PST + c0);
            const float* wr = W + h * 48 + c0;
            const float4 wA = ((const float4*)wr)[0];
            const float4 wB = ((const float4*)wr)[1];
            const short8 bf = mk8(pk(f2bf(wA.x), f2bf(wA.y)), pk(f2bf(wA.z), f2bf(wA.w)),
                                  pk(f2bf(wB.x), f2bf(wB.y)), pk(f2bf(wB.z), f2bf(wB.w)));
            acc = __builtin_amdgcn_mfma_f32_32x32x16_bf16(af, bf, acc, 0, 0, 0);
        }

        #pragma unroll
        for (int r = 0; r < 16; ++r) {
            const int row = (r & 3) + 8 * (r >> 2) + 4 * kh;   // node within block
            out[(size_t)(base + row) * HH + h] = acc[r];
        }
    }
}

extern "C" void kernel_launch(void* const* d_in, const int* in_sizes, int n_in,
                              void* d_out, int out_size, void* d_ws, size_t ws_size,
                              hipStream_t stream) {
    const float* x  = (const float*)d_in[0];
    const int*   ei = (const int*)d_in[1];
    const float* kv = (const float*)d_in[2];
    const float* W  = (const float*)d_in[3];
    float* out = (float*)d_out;

    unsigned short* xb = (unsigned short*)d_ws;            // 4.8 MB scratch
    const int n4 = NN * DD / 4;                            // 600000
    xcvt<<<(n4 + 255) / 256, 256, 0, stream>>>(x, xb, n4);

    const int grid = NN / NPB;                             // 3125, exact
    gnn<<<grid, TPB, 0, stream>>>(xb, ei, kv, W, out);
}